// Round 8
// baseline (4862.898 us; speedup 1.0000x reference)
//
#include <hip/hip_runtime.h>
#include <hip/hip_bf16.h>
#include <stdint.h>
#include <stddef.h>

// NeuralODE y'=MLP(y), dopri 6-stage RK, 240 sequential MLP evals.
// Round 8 = round 7 with the LDS-overflow bug fixed: the 1024-thread x0
// pre-staging block wrote 32 rows into 16-row sA, corrupting the LDS weight
// cache. Removed (store_stage(yy) already covers sA fully).
// Structure: 64 WGs x 16 rows, 16 waves/WG (4/SIMD). Weight placement:
//   - 10 chunks/wave (40 VGPR) register-pinned
//   - 6 chunks/wave in LDS (96 KB/CU)
//   - 48 chunks/wave streamed from L2 via depth-6 rotating register queue,
//     continuous across layers AND evals (48 % 6 == 0); refills stay in
//     flight across lgkm-only barriers.
// Chunk = one MFMA A-fragment for the whole wave = 1 KB (lane*16B, swizzled
// by cvt_w so every load is one coalesced dwordx4).

typedef __bf16 bf16x8 __attribute__((ext_vector_type(8)));
typedef __bf16 bf16x4 __attribute__((ext_vector_type(4)));
typedef float  f32x4  __attribute__((ext_vector_type(4)));
typedef int    i32x4  __attribute__((ext_vector_type(4)));

#define DD 256
#define HH 512
#define RA 264   // sA row stride 528B
#define RH 520   // sH row stride 1040B

#define W1P_OFF 0
#define W2P_OFF 131072            // 512*256
#define W3P_OFF (131072+262144)   // + 512*512

#define MFMA(A,B,C) __builtin_amdgcn_mfma_f32_16x16x32_bf16((A),(B),(C),0,0,0)
#define BC(X) __builtin_bit_cast(bf16x8, (X))

// Swizzle: Wp[(t*KB + kb)*64 + lane][8] = W[t*16 + (lane&15)][kb*32 + (lane>>4)*8 ..+8]
__global__ void cvt_w(const float* __restrict__ W1, const float* __restrict__ W2,
                      const float* __restrict__ W3, __bf16* __restrict__ o)
{
    int i = blockIdx.x * blockDim.x + threadIdx.x;   // 0..65535
    const float* src;
    __bf16* dst;
    if (i < 16384) {              // W1: 32 tiles x 8 kb x 64 lanes
        int c = i, lane = c & 63, kb = (c >> 6) & 7, t = c >> 9;
        src = W1 + (size_t)(t*16 + (lane & 15))*DD + kb*32 + (lane >> 4)*8;
        dst = o + W1P_OFF + (size_t)c*8;
    } else if (i < 49152) {       // W2: 32 tiles x 16 kb x 64 lanes
        int c = i - 16384, lane = c & 63, kb = (c >> 6) & 15, t = c >> 10;
        src = W2 + (size_t)(t*16 + (lane & 15))*HH + kb*32 + (lane >> 4)*8;
        dst = o + W2P_OFF + (size_t)c*8;
    } else {                      // W3: 16 tiles x 16 kb x 64 lanes
        int c = i - 49152, lane = c & 63, kb = (c >> 6) & 15, t = c >> 10;
        src = W3 + (size_t)(t*16 + (lane & 15))*HH + kb*32 + (lane >> 4)*8;
        dst = o + W3P_OFF + (size_t)c*8;
    }
#pragma unroll
    for (int e = 0; e < 8; ++e) dst[e] = (__bf16)src[e];
}

// LDS-only barrier: streamed weight loads (vmcnt) stay in flight across it.
__device__ __forceinline__ void wg_barrier() {
    asm volatile("s_waitcnt lgkmcnt(0)" ::: "memory");
    __builtin_amdgcn_s_barrier();
    asm volatile("" ::: "memory");
}

__global__ __launch_bounds__(1024) __attribute__((amdgpu_waves_per_eu(4, 4)))
void ode_kernel(const float* __restrict__ x0, const int* __restrict__ Tp,
                const __bf16* __restrict__ Wp,
                const float* __restrict__ b1, const float* __restrict__ b2,
                const float* __restrict__ b3, float* __restrict__ out)
{
    __shared__ __bf16 sA [16 * RA];        // y_stage [16][256]
    __shared__ __bf16 sH1[16 * RH];        // h1      [16][512]
    __shared__ __bf16 sH2[16 * RH];        // h2      [16][512]
    __shared__ __bf16 lwcs[16 * 6 * 512];  // 96 KB LDS weight cache
    __shared__ float  sb1[HH], sb2[HH], sb3[DD];

    const int   nT = *Tp - 1;
    const float hs = 10.0f / (float)nT * 0.25f;

    const int tid  = threadIdx.x;
    const int w    = tid >> 6;    // wave: neurons [w*32,+32) L1/L2, dims [w*16,+16) L3
    const int lane = tid & 63;
    const int lr   = lane & 15;
    const int lg   = lane >> 4;
    const int brow = blockIdx.x * 16 + lr;

    const int o1 = w * 8192;                 // W1 wave base (elems)
    const int o2 = W2P_OFF + w * 16384;      // W2 wave base
    const int o3 = W3P_OFF + w * 8192;       // W3 wave base
    const __bf16* wpl = Wp + lane * 8;       // per-lane base

    // ---- pinned weight registers: 10 chunks = 40 VGPR ----
    i32x4 pw0 = *(const i32x4*)(wpl + o1);                  // W1 t0 kb0
    i32x4 pw1 = *(const i32x4*)(wpl + o1 + 4096);           // W1 t1 kb0
    i32x4 pw2 = *(const i32x4*)(wpl + o2);                  // W2 t0 kb0
    i32x4 pw3 = *(const i32x4*)(wpl + o2 + 8192);           // W2 t1 kb0
    i32x4 pw4 = *(const i32x4*)(wpl + o2 + 512);            // W2 t0 kb1
    i32x4 pw5 = *(const i32x4*)(wpl + o2 + 8192 + 512);     // W2 t1 kb1
    i32x4 pw6 = *(const i32x4*)(wpl + o3);                  // W3 kb0
    i32x4 pw7 = *(const i32x4*)(wpl + o3 + 512);            // W3 kb1
    i32x4 pw8 = *(const i32x4*)(wpl + o3 + 1024);           // W3 kb2
    i32x4 pw9 = *(const i32x4*)(wpl + o3 + 1536);           // W3 kb3
    asm volatile("" : "+v"(pw0), "+v"(pw1), "+v"(pw2), "+v"(pw3), "+v"(pw4));
    asm volatile("" : "+v"(pw5), "+v"(pw6), "+v"(pw7), "+v"(pw8), "+v"(pw9));

    // ---- LDS weight cache: 6 chunks/wave ----
    // lc0/1 = W1 t0/t1 kb1; lc2/3 = W2 t0/t1 kb2; lc4/5 = W3 kb4/5
    {
        const int coff[6] = { o1 + 512, o1 + 4096 + 512,
                              o2 + 1024, o2 + 8192 + 1024,
                              o3 + 2048, o3 + 2560 };
#pragma unroll
        for (int c = 0; c < 6; ++c) {
            i32x4 v = *(const i32x4*)(wpl + coff[c]);
            *(i32x4*)(lwcs + (w*6 + c)*512 + lane*8) = v;
        }
    }
    const __bf16* lwc = lwcs + w * 6 * 512 + lane * 8;

    if (tid < HH) { sb1[tid] = b1[tid]; sb2[tid] = b2[tid]; }
    if (tid < DD) { sb3[tid] = b3[tid]; }

    // ---- stream queue prologue: L1 chunks 0..5 of eval 0 ----
    i32x4 wq[6];
#pragma unroll
    for (int j = 0; j < 6; ++j)
        wq[j] = *(const i32x4*)(wpl + o1 + (j & 1)*4096 + (2 + j/2)*512);

    f32x4 yy = *(const f32x4*)(x0 + (size_t)brow * DD + w*16 + lg*4);
    f32x4 k1, k2, k3, k4, k5, k6;

    __bf16*       sAw  = sA  + lr*RA + w*16 + lg*4;
    __bf16*       sH1w = sH1 + lr*RH + w*32 + lg*4;
    __bf16*       sH2w = sH2 + lr*RH + w*32 + lg*4;
    const __bf16* apA  = sA  + lr*RA + lg*8;
    const __bf16* apH1 = sH1 + lr*RH + lg*8;
    const __bf16* apH2 = sH2 + lr*RH + lg*8;

    auto store_stage = [&](f32x4 v) {   // covers all 16 rows x 256 dims exactly
        bf16x4 o;
#pragma unroll
        for (int j = 0; j < 4; ++j) o[j] = (__bf16)v[j];
        *(bf16x4*)sAw = o;
    };

    auto mlp = [&](f32x4& kout) {
        wg_barrier();                              // sA ready (startup: lwcs/sb too)
        // ======== L1: K=256, tiles t0,t1 ========
        f32x4 a0 = *(const f32x4*)(sb1 + w*32 + lg*4);
        f32x4 a1 = *(const f32x4*)(sb1 + w*32 + 16 + lg*4);
        {
            bf16x8 b = *(const bf16x8*)(apA + 0*32);           // kb0: pinned
            a0 = MFMA(BC(pw0), b, a0);
            a1 = MFMA(BC(pw1), b, a1);
            b = *(const bf16x8*)(apA + 1*32);                  // kb1: LDS
            a0 = MFMA(*(const bf16x8*)(lwc + 0*512), b, a0);
            a1 = MFMA(*(const bf16x8*)(lwc + 1*512), b, a1);
        }
#pragma unroll
        for (int j = 0; j < 12; ++j) {                         // kb2..7 streamed
            const int kb = 2 + j/2;
            bf16x8 b  = *(const bf16x8*)(apA + kb*32);
            bf16x8 wa = BC(wq[j % 6]);
            const int nj = j + 6;
            const int noff = (nj < 12)
                ? (o1 + (nj & 1)*4096 + (2 + nj/2)*512)                  // L1 chunk nj
                : (o2 + ((nj-12) & 1)*8192 + (3 + (nj-12)/2)*512);       // L2 chunk nj-12
            wq[j % 6] = *(const i32x4*)(wpl + noff);
            if ((j & 1) == 0) a0 = MFMA(wa, b, a0); else a1 = MFMA(wa, b, a1);
        }
        {
            bf16x4 v0, v1;
#pragma unroll
            for (int j = 0; j < 4; ++j) {
                v0[j] = (__bf16)fmaxf(a0[j], 0.0f);
                v1[j] = (__bf16)fmaxf(a1[j], 0.0f);
            }
            *(bf16x4*)sH1w        = v0;
            *(bf16x4*)(sH1w + 16) = v1;
        }
        wg_barrier();                              // h1 ready
        // ======== L2: K=512, tiles t0,t1 ========
        a0 = *(const f32x4*)(sb2 + w*32 + lg*4);
        a1 = *(const f32x4*)(sb2 + w*32 + 16 + lg*4);
        {
            bf16x8 b = *(const bf16x8*)(apH1 + 0*32);          // kb0: pinned
            a0 = MFMA(BC(pw2), b, a0);
            a1 = MFMA(BC(pw3), b, a1);
            b = *(const bf16x8*)(apH1 + 1*32);                 // kb1: pinned
            a0 = MFMA(BC(pw4), b, a0);
            a1 = MFMA(BC(pw5), b, a1);
            b = *(const bf16x8*)(apH1 + 2*32);                 // kb2: LDS
            a0 = MFMA(*(const bf16x8*)(lwc + 2*512), b, a0);
            a1 = MFMA(*(const bf16x8*)(lwc + 3*512), b, a1);
        }
#pragma unroll
        for (int j = 0; j < 26; ++j) {                         // kb3..15 streamed
            const int kb = 3 + j/2;
            bf16x8 b  = *(const bf16x8*)(apH1 + kb*32);
            bf16x8 wa = BC(wq[j % 6]);
            const int noff = (j < 20)
                ? (o2 + ((j+6) & 1)*8192 + (3 + (j+6)/2)*512)            // L2 chunk j+6
                : (o3 + (6 + (j-20))*512);                               // L3 chunk j-20
            wq[j % 6] = *(const i32x4*)(wpl + noff);
            if ((j & 1) == 0) a0 = MFMA(wa, b, a0); else a1 = MFMA(wa, b, a1);
        }
        {
            bf16x4 v0, v1;
#pragma unroll
            for (int j = 0; j < 4; ++j) {
                v0[j] = (__bf16)fmaxf(a0[j], 0.0f);
                v1[j] = (__bf16)fmaxf(a1[j], 0.0f);
            }
            *(bf16x4*)sH2w        = v0;
            *(bf16x4*)(sH2w + 16) = v1;
        }
        wg_barrier();                              // h2 ready
        // ======== L3: K=512, 1 tile ========
        f32x4 a = *(const f32x4*)(sb3 + w*16 + lg*4);
        {
            bf16x8 b = *(const bf16x8*)(apH2 + 0*32);          // kb0..3: pinned
            a = MFMA(BC(pw6), b, a);
            b = *(const bf16x8*)(apH2 + 1*32);
            a = MFMA(BC(pw7), b, a);
            b = *(const bf16x8*)(apH2 + 2*32);
            a = MFMA(BC(pw8), b, a);
            b = *(const bf16x8*)(apH2 + 3*32);
            a = MFMA(BC(pw9), b, a);
            b = *(const bf16x8*)(apH2 + 4*32);                 // kb4/5: LDS
            a = MFMA(*(const bf16x8*)(lwc + 4*512), b, a);
            b = *(const bf16x8*)(apH2 + 5*32);
            a = MFMA(*(const bf16x8*)(lwc + 5*512), b, a);
        }
#pragma unroll
        for (int j = 0; j < 10; ++j) {                         // kb6..15 streamed
            const int kb = 6 + j;
            bf16x8 b  = *(const bf16x8*)(apH2 + kb*32);
            bf16x8 wa = BC(wq[(2 + j) % 6]);
            const int noff = (j < 4)
                ? (o3 + (12 + j)*512)                                    // L3 kb 12+j
                : (o1 + ((j-4) & 1)*4096 + (2 + (j-4)/2)*512);           // wrap: next eval L1
            wq[(2 + j) % 6] = *(const i32x4*)(wpl + noff);
            a = MFMA(wa, b, a);
        }
        kout = a;
    };

    for (int t = 0; t < nT; ++t) {
        for (int ss = 0; ss < 4; ++ss) {
            store_stage(yy);
            mlp(k1);

            store_stage(yy + hs * (0.2f * k1));
            mlp(k2);

            store_stage(yy + hs * ((3.0f/40.0f)*k1 + (9.0f/40.0f)*k2));
            mlp(k3);

            store_stage(yy + hs * ((float)(44.0/45.0)*k1 - (float)(56.0/15.0)*k2
                                  + (float)(32.0/9.0)*k3));
            mlp(k4);

            store_stage(yy + hs * ((float)(19372.0/6561.0)*k1 - (float)(25360.0/2187.0)*k2
                                  + (float)(64448.0/6561.0)*k3 - (float)(212.0/729.0)*k4));
            mlp(k5);

            store_stage(yy + hs * ((float)(9017.0/3168.0)*k1 - (float)(355.0/33.0)*k2
                                  + (float)(46732.0/5247.0)*k3 + (float)(49.0/176.0)*k4
                                  - (float)(5103.0/18656.0)*k5));
            mlp(k6);

            yy = yy + hs * ((float)(35.0/384.0)*k1 + (float)(500.0/1113.0)*k3
                           + (float)(125.0/192.0)*k4 + (float)(-2187.0/6784.0)*k5
                           + (float)(11.0/84.0)*k6);
        }
        *(f32x4*)(out + ((size_t)brow * nT + t) * DD + w*16 + lg*4) = yy;
    }
}

extern "C" void kernel_launch(void* const* d_in, const int* in_sizes, int n_in,
                              void* d_out, int out_size, void* d_ws, size_t ws_size,
                              hipStream_t stream)
{
    const float* x0 = (const float*)d_in[0];
    const int*   Tp = (const int*)  d_in[1];
    const float* W1 = (const float*)d_in[2];
    const float* b1 = (const float*)d_in[3];
    const float* W2 = (const float*)d_in[4];
    const float* b2 = (const float*)d_in[5];
    const float* W3 = (const float*)d_in[6];
    const float* b3 = (const float*)d_in[7];

    const int B = in_sizes[0] / DD;      // 1024

    __bf16* wb = (__bf16*)d_ws;          // 1 MiB swizzled bf16 weights
    cvt_w<<<256, 256, 0, stream>>>(W1, W2, W3, wb);

    ode_kernel<<<B / 16, 1024, 0, stream>>>(x0, Tp, wb, b1, b2, b3, (float*)d_out);
}

// Round 9
// 4003.386 us; speedup vs baseline: 1.2147x; 1.2147x over previous
//
#include <hip/hip_runtime.h>
#include <hip/hip_bf16.h>
#include <stdint.h>
#include <stddef.h>

// NeuralODE y'=MLP(y), dopri 6-stage RK, 240 sequential MLP evals.
// Round 9: r6 base (64 WGs x 16 rows, 16 waves/WG, 4/SIMD, zero scratch) +
// weight streaming via global_load_lds ring. Per wave: 4-slot x 1KB LDS ring;
// 64 chunks/eval streamed in fixed order (64%4==0 -> slot phase repeats each
// eval; ring runs continuously across evals and across lgkm-only barriers).
// Counted vmcnt(2)/(3) before consume (never 0 in-loop); slot WAR closed by a
// free lgkmcnt(0) after the consuming MFMAs, before the refill issue.
// No register-resident weights AT ALL (r8 lesson: the allocator demotes them
// to scratch -> 2 MB/XCD hot scratch -> L2 thrash -> 2.4 GB HBM refetch).
// In-flight: 4KB/wave x 16 waves = 64KB/CU >> latency*BW -> L2 port saturated.

typedef __bf16 bf16x8 __attribute__((ext_vector_type(8)));
typedef __bf16 bf16x4 __attribute__((ext_vector_type(4)));
typedef float  f32x4  __attribute__((ext_vector_type(4)));

#define DD 256
#define HH 512
#define RA 264   // sA row stride 528B
#define RH 520   // sH row stride 1040B

#define W1P_OFF 0
#define W2P_OFF 131072            // 512*256
#define W3P_OFF (131072+262144)   // + 512*512

#define MFMA(A,B,C) __builtin_amdgcn_mfma_f32_16x16x32_bf16((A),(B),(C),0,0,0)
#define VMWAIT(N) asm volatile("s_waitcnt vmcnt(" #N ")" ::: "memory")
#define LGKM0()   asm volatile("s_waitcnt lgkmcnt(0)" ::: "memory")

// Swizzle: Wp[(t*KB + kb)*64 + lane][8] = W[t*16 + (lane&15)][kb*32 + (lane>>4)*8 ..+8]
// -> every 1KB chunk is lane-contiguous: exactly global_load_lds's linear layout.
__global__ void cvt_w(const float* __restrict__ W1, const float* __restrict__ W2,
                      const float* __restrict__ W3, __bf16* __restrict__ o)
{
    int i = blockIdx.x * blockDim.x + threadIdx.x;   // 0..65535
    const float* src;
    __bf16* dst;
    if (i < 16384) {              // W1: 32 tiles x 8 kb x 64 lanes
        int c = i, lane = c & 63, kb = (c >> 6) & 7, t = c >> 9;
        src = W1 + (size_t)(t*16 + (lane & 15))*DD + kb*32 + (lane >> 4)*8;
        dst = o + W1P_OFF + (size_t)c*8;
    } else if (i < 49152) {       // W2: 32 tiles x 16 kb x 64 lanes
        int c = i - 16384, lane = c & 63, kb = (c >> 6) & 15, t = c >> 10;
        src = W2 + (size_t)(t*16 + (lane & 15))*HH + kb*32 + (lane >> 4)*8;
        dst = o + W2P_OFF + (size_t)c*8;
    } else {                      // W3: 16 tiles x 16 kb x 64 lanes
        int c = i - 49152, lane = c & 63, kb = (c >> 6) & 15, t = c >> 10;
        src = W3 + (size_t)(t*16 + (lane & 15))*HH + kb*32 + (lane >> 4)*8;
        dst = o + W3P_OFF + (size_t)c*8;
    }
#pragma unroll
    for (int e = 0; e < 8; ++e) dst[e] = (__bf16)src[e];
}

// LDS-only barrier: in-flight global_load_lds (vmcnt) survives it.
__device__ __forceinline__ void wg_barrier() {
    asm volatile("s_waitcnt lgkmcnt(0)" ::: "memory");
    __builtin_amdgcn_s_barrier();
    asm volatile("" ::: "memory");
}

// global -> LDS direct DMA, 16B/lane = 1KB/wave. LDS dest is wave-uniform
// base (+ lane*16 by HW). Low 32 bits of a generic LDS pointer ARE the LDS
// byte address on gfx9+ (addrspacecast AS3->generic zero-extends).
typedef __attribute__((address_space(3))) uint32_t       lds_u32;
typedef const __attribute__((address_space(1))) uint32_t g_u32;
__device__ __forceinline__ void dma16(const __bf16* g, __bf16* l) {
    __builtin_amdgcn_global_load_lds((g_u32*)(uintptr_t)g,
                                     (lds_u32*)(uint32_t)(uintptr_t)l, 16, 0, 0);
}

// chunk index c (0..63, per-eval order) -> element offset in Wp for wave w:
//  c 0..15 : L1, t=c&1, kb=c>>1
//  c 16..47: L2, t=(c-16)&1, kb=(c-16)>>1
//  c 48..63: L3, kb=c-48
__device__ __forceinline__ int chunk_off(int w, int c) {
    if (c < 16) return w*8192 + (c&1)*4096 + (c>>1)*512;
    if (c < 48) return W2P_OFF + w*16384 + ((c-16)&1)*8192 + ((c-16)>>1)*512;
    return W3P_OFF + w*8192 + (c-48)*512;
}

__global__ __launch_bounds__(1024) __attribute__((amdgpu_waves_per_eu(4, 4)))
void ode_kernel(const float* __restrict__ x0, const int* __restrict__ Tp,
                const __bf16* __restrict__ Wp,
                const float* __restrict__ b1, const float* __restrict__ b2,
                const float* __restrict__ b3, float* __restrict__ out)
{
    __shared__ __bf16 sA [16 * RA];        // y_stage [16][256]
    __shared__ __bf16 sH1[16 * RH];        // h1      [16][512]
    __shared__ __bf16 sH2[16 * RH];        // h2      [16][512]
    __shared__ __bf16 stage[16 * 4 * 512]; // 64 KB: per-wave 4-slot x 1KB ring
    __shared__ float  sb1[HH], sb2[HH], sb3[DD];

    const int   nT = *Tp - 1;
    const float hs = 10.0f / (float)nT * 0.25f;

    const int tid  = threadIdx.x;
    const int w    = tid >> 6;    // wave: neurons [w*32,+32) L1/L2, dims [w*16,+16) L3
    const int lane = tid & 63;
    const int lr   = lane & 15;
    const int lg   = lane >> 4;
    const int brow = blockIdx.x * 16 + lr;

    const __bf16* wpl  = Wp + lane * 8;          // per-lane global base
    __bf16*       ring = stage + w * 4 * 512;    // wave-uniform ring base
    const __bf16* rgl  = ring + lane * 8;        // per-lane ring read base

    auto dma = [&](int c) {                      // c may be >=64 (wraps to next eval)
        dma16(wpl + chunk_off(w, c & 63), ring + (c & 3) * 512);
    };

    if (tid < HH) { sb1[tid] = b1[tid]; sb2[tid] = b2[tid]; }
    if (tid < DD) { sb3[tid] = b3[tid]; }

    // RK state: lane holds dims [w*16+lg*4, +4) of batch row lr
    f32x4 yy = *(const f32x4*)(x0 + (size_t)brow * DD + w*16 + lg*4);
    f32x4 k1, k2, k3, k4, k5, k6;

    __bf16*       sAw  = sA  + lr*RA + w*16 + lg*4;
    __bf16*       sH1w = sH1 + lr*RH + w*32 + lg*4;
    __bf16*       sH2w = sH2 + lr*RH + w*32 + lg*4;
    const __bf16* apA  = sA  + lr*RA + lg*8;
    const __bf16* apH1 = sH1 + lr*RH + lg*8;
    const __bf16* apH2 = sH2 + lr*RH + lg*8;

    // ---- ring prologue: fill 4 slots (chunks 0..3 of eval 0) ----
    dma(0); dma(1); dma(2); dma(3);

    auto store_stage = [&](f32x4 v) {
        bf16x4 o;
#pragma unroll
        for (int j = 0; j < 4; ++j) o[j] = (__bf16)v[j];
        *(bf16x4*)sAw = o;
    };

    auto mlp = [&](f32x4& kout) {
        wg_barrier();                              // sA ready (lgkm only)
        // ======== L1: K=256, tiles t0,t1 (chunks 0..15) ========
        f32x4 a0 = *(const f32x4*)(sb1 + w*32 + lg*4);
        f32x4 a1 = *(const f32x4*)(sb1 + w*32 + 16 + lg*4);
#pragma unroll
        for (int kb = 0; kb < 8; ++kb) {
            const int c0 = 2*kb;
            VMWAIT(2);                             // chunks c0,c0+1 landed
            bf16x8 b   = *(const bf16x8*)(apA + kb*32);
            bf16x8 wa0 = *(const bf16x8*)(rgl + ((c0    ) & 3)*512);
            bf16x8 wa1 = *(const bf16x8*)(rgl + ((c0 + 1) & 3)*512);
            a0 = MFMA(wa0, b, a0);
            a1 = MFMA(wa1, b, a1);
            LGKM0();                               // slot reads retired (free)
            dma(c0 + 4); dma(c0 + 5);              // refill -> WAR-safe
        }
        {
            bf16x4 v0, v1;
#pragma unroll
            for (int j = 0; j < 4; ++j) {
                v0[j] = (__bf16)fmaxf(a0[j], 0.0f);
                v1[j] = (__bf16)fmaxf(a1[j], 0.0f);
            }
            *(bf16x4*)sH1w        = v0;
            *(bf16x4*)(sH1w + 16) = v1;
        }
        wg_barrier();                              // h1 ready
        // ======== L2: K=512, tiles t0,t1 (chunks 16..47) ========
        a0 = *(const f32x4*)(sb2 + w*32 + lg*4);
        a1 = *(const f32x4*)(sb2 + w*32 + 16 + lg*4);
#pragma unroll
        for (int kb = 0; kb < 16; ++kb) {
            const int c0 = 16 + 2*kb;
            VMWAIT(2);
            bf16x8 b   = *(const bf16x8*)(apH1 + kb*32);
            bf16x8 wa0 = *(const bf16x8*)(rgl + ((c0    ) & 3)*512);
            bf16x8 wa1 = *(const bf16x8*)(rgl + ((c0 + 1) & 3)*512);
            a0 = MFMA(wa0, b, a0);
            a1 = MFMA(wa1, b, a1);
            LGKM0();
            dma(c0 + 4); dma(c0 + 5);
        }
        {
            bf16x4 v0, v1;
#pragma unroll
            for (int j = 0; j < 4; ++j) {
                v0[j] = (__bf16)fmaxf(a0[j], 0.0f);
                v1[j] = (__bf16)fmaxf(a1[j], 0.0f);
            }
            *(bf16x4*)sH2w        = v0;
            *(bf16x4*)(sH2w + 16) = v1;
        }
        wg_barrier();                              // h2 ready
        // ======== L3: K=512, 1 tile (chunks 48..63) ========
        f32x4 a = *(const f32x4*)(sb3 + w*16 + lg*4);
#pragma unroll
        for (int kb = 0; kb < 16; ++kb) {
            const int c = 48 + kb;
            VMWAIT(3);
            bf16x8 b  = *(const bf16x8*)(apH2 + kb*32);
            bf16x8 wa = *(const bf16x8*)(rgl + (c & 3)*512);
            a = MFMA(wa, b, a);
            LGKM0();
            dma(c + 4);                            // c>=60 wraps: next eval's L1
        }
        kout = a;
    };

    for (int t = 0; t < nT; ++t) {
        for (int ss = 0; ss < 4; ++ss) {
            store_stage(yy);
            mlp(k1);

            store_stage(yy + hs * (0.2f * k1));
            mlp(k2);

            store_stage(yy + hs * ((3.0f/40.0f)*k1 + (9.0f/40.0f)*k2));
            mlp(k3);

            store_stage(yy + hs * ((float)(44.0/45.0)*k1 - (float)(56.0/15.0)*k2
                                  + (float)(32.0/9.0)*k3));
            mlp(k4);

            store_stage(yy + hs * ((float)(19372.0/6561.0)*k1 - (float)(25360.0/2187.0)*k2
                                  + (float)(64448.0/6561.0)*k3 - (float)(212.0/729.0)*k4));
            mlp(k5);

            store_stage(yy + hs * ((float)(9017.0/3168.0)*k1 - (float)(355.0/33.0)*k2
                                  + (float)(46732.0/5247.0)*k3 + (float)(49.0/176.0)*k4
                                  - (float)(5103.0/18656.0)*k5));
            mlp(k6);

            yy = yy + hs * ((float)(35.0/384.0)*k1 + (float)(500.0/1113.0)*k3
                           + (float)(125.0/192.0)*k4 + (float)(-2187.0/6784.0)*k5
                           + (float)(11.0/84.0)*k6);
        }
        *(f32x4*)(out + ((size_t)brow * nT + t) * DD + w*16 + lg*4) = yy;
    }
    VMWAIT(0);   // retire trailing ring DMAs + out stores before endpgm
}

extern "C" void kernel_launch(void* const* d_in, const int* in_sizes, int n_in,
                              void* d_out, int out_size, void* d_ws, size_t ws_size,
                              hipStream_t stream)
{
    const float* x0 = (const float*)d_in[0];
    const int*   Tp = (const int*)  d_in[1];
    const float* W1 = (const float*)d_in[2];
    const float* b1 = (const float*)d_in[3];
    const float* W2 = (const float*)d_in[4];
    const float* b2 = (const float*)d_in[5];
    const float* W3 = (const float*)d_in[6];
    const float* b3 = (const float*)d_in[7];

    const int B = in_sizes[0] / DD;      // 1024

    __bf16* wb = (__bf16*)d_ws;          // 1 MiB swizzled bf16 weights
    cvt_w<<<256, 256, 0, stream>>>(W1, W2, W3, wb);

    ode_kernel<<<B / 16, 1024, 0, stream>>>(x0, Tp, wb, b1, b2, b3, (float*)d_out);
}